// Round 12
// baseline (1038.043 us; speedup 1.0000x reference)
//
#include <hip/hip_runtime.h>

#define Hh 1024
#define NBATCH 128
#define TSTEPS 256
#define DOUT 1024
#define SLOT (NBATCH * Hh)

typedef _Float16 half8 __attribute__((ext_vector_type(8)));
typedef float floatx4 __attribute__((ext_vector_type(4)));

__device__ __forceinline__ float fast_sigmoid(float x) {
  float e = __expf(-x);
  return __builtin_amdgcn_rcpf(1.0f + e);
}
__device__ __forceinline__ float fast_tanh(float x) {
  x = fminf(15.0f, fmaxf(-15.0f, x));
  float e = __expf(-2.0f * x);
  return 1.0f - 2.0f * e * __builtin_amdgcn_rcpf(1.0f + e);
}

__device__ __forceinline__ half8 cvt8(float4 x, float4 y) {
  half8 h = {(_Float16)x.x, (_Float16)x.y, (_Float16)x.z, (_Float16)x.w,
             (_Float16)y.x, (_Float16)y.y, (_Float16)y.z, (_Float16)y.w};
  return h;
}

// Fused persistent kernel (round-10 proven core: 877us): 256 WGs, 512
// threads = 8 waves, all running the lstm persona at K=128 + distributed fc
// (zero extra A-loads). Sync = v6 discipline verbatim (two __syncthreads,
// drain-then-WG-flag by tid 0, per-wave 4-producer poll, all-lane poll
// loads -- the v10 byte-proven form).
//
// v12: NO PREP DISPATCH. Weights are loaded directly from the f32 inputs
// and converted in-register (B from W_ih, then W_ih+W_hh summed at load;
// Bfc from W_fc; bias = b_ih+b_hh). Step 0's A-fragments convert from f32
// hT directly (hs slot 0 unused). Conversion ops identical to the old
// prep's -> bit-exact results. Only external init: flags zeroed by a
// hipMemsetAsync before launch.
__global__ __launch_bounds__(512, 2) void lstm_kernel(
    const float* __restrict__ W_ih, const float* __restrict__ W_hh,
    const float* __restrict__ b_ih, const float* __restrict__ b_hh,
    const float* __restrict__ hT, const float* __restrict__ W_fc,
    const float* __restrict__ b_fc, _Float16* __restrict__ hs,
    unsigned* __restrict__ flags, float* __restrict__ out) {
  unsigned* xcd_ctr = flags + 256;
  const int tid = threadIdx.x;
  const int wave = tid >> 6;  // 0..7
  const int lane = tid & 63;
  const int l15 = lane & 15;
  const int quad = lane >> 4;

  __shared__ unsigned role_sh;
  {
    unsigned xcd;
    asm volatile("s_getreg_b32 %0, hwreg(HW_REG_XCC_ID)" : "=s"(xcd));
    if (tid == 0) role_sh = (xcd << 8) | atomicAdd(&xcd_ctr[xcd], 1u);
  }
  __syncthreads();
  const int g = role_sh >> 8;    // physical XCD == n-group
  const int jb = role_sh & 255;  // 0..31 within the XCD
  const int n0 = g * 16;
  const int j0 = jb * 32;
  const int kbase = wave * 128;      // this wave's K-range
  const int oc = wave & 1;           // 16-col half of the 32-col j-block
  const int rp = (wave >> 1) & 1;    // accumulator reg-pair
  const int rr = (wave >> 2) & 1;    // element within the pair
  unsigned* gflags = flags + g * 32;
  unsigned* pollp = gflags + wave * 4 + (lane & 3);  // 4 producers cover K-range

  __shared__ float2 part[8][2][4][2][64];   // 64KB lstm partials
  __shared__ floatx4 fcpart[8][2][64];      // 16KB fc partials

  float bias[4];
#pragma unroll
  for (int gt = 0; gt < 4; ++gt) {
    int idx = gt * 1024 + j0 + oc * 16 + l15;
    bias[gt] = b_ih[idx] + b_hh[idx];
  }

  // fc reduce role: thread tid owns out element (row fc_row, col fc_col)
  const int fc_col = tid & 31;
  const int fc_row = tid >> 5;  // 0..15
  const float bfc = b_fc[j0 + fc_col];
  const int fc_half = fc_col >> 4;
  const int fc_lsrc = (fc_row >> 2) * 16 + (fc_col & 15);
  const int fc_comp = fc_row & 3;

  half8 B[4][2][4];   // 128 regs lstm weights
  half8 Bfc[2][4];    // 32 regs fc weights (this wave's K-chunk)
  float cst = 0.0f;   // persistent cell state

  // Load lstm weights from f32 W_ih (step 0): convert in-register.
  auto load_B_ih = [&]() {
#pragma unroll
    for (int gt = 0; gt < 4; ++gt)
#pragma unroll
      for (int ct = 0; ct < 2; ++ct) {
        const float* p =
            W_ih + (size_t)(gt * 1024 + j0 + ct * 16 + l15) * Hh + kbase + quad * 8;
#pragma unroll
        for (int ks = 0; ks < 4; ++ks) {
          float4 x = *(const float4*)(p + ks * 32);
          float4 y = *(const float4*)(p + ks * 32 + 4);
          B[gt][ct][ks] = cvt8(x, y);
        }
      }
  };
  // Load W_sum = W_ih + W_hh (steps 1..255): sum in f32, convert.
  auto load_B_sum = [&]() {
#pragma unroll
    for (int gt = 0; gt < 4; ++gt)
#pragma unroll
      for (int ct = 0; ct < 2; ++ct) {
        size_t off = (size_t)(gt * 1024 + j0 + ct * 16 + l15) * Hh + kbase + quad * 8;
        const float* p1 = W_ih + off;
        const float* p2 = W_hh + off;
#pragma unroll
        for (int ks = 0; ks < 4; ++ks) {
          float4 x1 = *(const float4*)(p1 + ks * 32);
          float4 y1 = *(const float4*)(p1 + ks * 32 + 4);
          float4 x2 = *(const float4*)(p2 + ks * 32);
          float4 y2 = *(const float4*)(p2 + ks * 32 + 4);
          float4 xs = {x1.x + x2.x, x1.y + x2.y, x1.z + x2.z, x1.w + x2.w};
          float4 ys = {y1.x + y2.x, y1.y + y2.y, y1.z + y2.z, y1.w + y2.w};
          B[gt][ct][ks] = cvt8(xs, ys);
        }
      }
  };
  {
#pragma unroll
    for (int ct = 0; ct < 2; ++ct) {
      const float* p =
          W_fc + (size_t)(j0 + ct * 16 + l15) * Hh + kbase + quad * 8;
#pragma unroll
      for (int ks = 0; ks < 4; ++ks) {
        float4 x = *(const float4*)(p + ks * 32);
        float4 y = *(const float4*)(p + ks * 32 + 4);
        Bfc[ct][ks] = cvt8(x, y);
      }
    }
  }

  auto poll = [&](int tgt) {
    while (1) {
      unsigned v = __hip_atomic_load(pollp, __ATOMIC_RELAXED, __HIP_MEMORY_SCOPE_AGENT);
      if (__all((int)(v >= (unsigned)tgt))) break;
    }
  };

  // One step given pre-loaded A-fragments. Byte-identical flow to v10.
  auto step_body = [&](const half8* a, _Float16* hdst, int s) {
    floatx4 acc[2][4] = {};
    floatx4 f0 = {}, f1 = {};
#pragma unroll
    for (int ks = 0; ks < 4; ++ks) {
#pragma unroll
      for (int ct = 0; ct < 2; ++ct)
#pragma unroll
        for (int gt = 0; gt < 4; ++gt)
          acc[ct][gt] =
              __builtin_amdgcn_mfma_f32_16x16x32_f16(a[ks], B[gt][ct][ks], acc[ct][gt], 0, 0, 0);
      if (s >= 1) {  // slot 0 = hT, not an fc input
        f0 = __builtin_amdgcn_mfma_f32_16x16x32_f16(a[ks], Bfc[0][ks], f0, 0, 0, 0);
        f1 = __builtin_amdgcn_mfma_f32_16x16x32_f16(a[ks], Bfc[1][ks], f1, 0, 0, 0);
      }
    }
#pragma unroll
    for (int ct = 0; ct < 2; ++ct)
#pragma unroll
      for (int gt = 0; gt < 4; ++gt) {
        float2 lo, hi;
        lo.x = acc[ct][gt][0]; lo.y = acc[ct][gt][1];
        hi.x = acc[ct][gt][2]; hi.y = acc[ct][gt][3];
        part[wave][ct][gt][0][lane] = lo;
        part[wave][ct][gt][1][lane] = hi;
      }
    if (s >= 1) {
      fcpart[wave][0][lane] = f0;
      fcpart[wave][1][lane] = f1;
    }
    __syncthreads();

    float gv[4];
#pragma unroll
    for (int gt = 0; gt < 4; ++gt) {
      float s2 = bias[gt];
#pragma unroll
      for (int src = 0; src < 8; ++src) {
        float2 p = part[src][oc][gt][rp][lane];
        s2 += rr ? p.y : p.x;
      }
      gv[gt] = s2;
    }
    {
      float ig = fast_sigmoid(gv[0]);
      float fg = fast_sigmoid(gv[1]);
      float gg = fast_tanh(gv[2]);
      float og = fast_sigmoid(gv[3]);
      float c = fg * cst + ig * gg;
      cst = c;
      float h = og * fast_tanh(c);
      int row = n0 + quad * 4 + rp * 2 + rr;
      _Float16 hv = (_Float16)h;
      unsigned short ub;
      __builtin_memcpy(&ub, &hv, 2);
      // agent write-through store (v6-proven); next barrier drains vmcnt.
      __hip_atomic_store((unsigned short*)(hdst + (size_t)row * Hh + j0 + oc * 16 + l15),
                         ub, __ATOMIC_RELAXED, __HIP_MEMORY_SCOPE_AGENT);
    }
    // fc reduce + out store, after the h store so h issues first.
    if (s >= 1) {
      float fsum = bfc;
#pragma unroll
      for (int src = 0; src < 8; ++src) fsum += fcpart[src][fc_half][fc_lsrc][fc_comp];
      out[((size_t)(n0 + fc_row) * TSTEPS + (s - 1)) * DOUT + j0 + fc_col] = fsum;
    }
    __syncthreads();  // drain: all h (and out) stores retired
    if (tid == 0) {
      __hip_atomic_store(&gflags[jb], (unsigned)(s + 1), __ATOMIC_RELAXED,
                         __HIP_MEMORY_SCOPE_AGENT);
    }
  };

  // Step 0: x = hT (f32, converted in-reg), hx = 0 => gates = hT@W_ih^T + b_sum
  load_B_ih();
  {
    half8 a[4];
    const float* ap = hT + (size_t)(n0 + l15) * Hh + kbase + quad * 8;
#pragma unroll
    for (int ks = 0; ks < 4; ++ks) {
      float4 x = *(const float4*)(ap + ks * 32);
      float4 y = *(const float4*)(ap + ks * 32 + 4);
      a[ks] = cvt8(x, y);
    }
    step_body(a, hs + SLOT, 0);
  }
  // Steps 1..255: x = hx = h => gates = h @ (W_ih+W_hh)^T + b_sum
  load_B_sum();
  for (int s = 1; s < TSTEPS; ++s) {
    poll(s);
    asm volatile("" ::: "memory");  // keep A-loads below the poll exit
    half8 a[4];
    const _Float16* hp =
        hs + (size_t)s * SLOT + (size_t)(n0 + l15) * Hh + kbase + quad * 8;
#pragma unroll
    for (int ks = 0; ks < 4; ++ks) a[ks] = *(const half8*)(hp + ks * 32);
    step_body(a, hs + (size_t)(s + 1) * SLOT, s);
  }

  // Epilogue: fc for slot 256 (out col 255). Flag 256 stored by all WGs.
  {
    unsigned* ep = gflags + (lane & 31);
    while (1) {
      unsigned v = __hip_atomic_load(ep, __ATOMIC_RELAXED, __HIP_MEMORY_SCOPE_AGENT);
      if (__all((int)(v >= (unsigned)TSTEPS))) break;
    }
    asm volatile("" ::: "memory");
    floatx4 f0 = {}, f1 = {};
    const _Float16* ap =
        hs + (size_t)TSTEPS * SLOT + (size_t)(n0 + l15) * Hh + kbase + quad * 8;
#pragma unroll
    for (int ks = 0; ks < 4; ++ks) {
      half8 a = *(const half8*)(ap + ks * 32);
      f0 = __builtin_amdgcn_mfma_f32_16x16x32_f16(a, Bfc[0][ks], f0, 0, 0, 0);
      f1 = __builtin_amdgcn_mfma_f32_16x16x32_f16(a, Bfc[1][ks], f1, 0, 0, 0);
    }
    fcpart[wave][0][lane] = f0;
    fcpart[wave][1][lane] = f1;
    __syncthreads();
    float fsum = bfc;
#pragma unroll
    for (int src = 0; src < 8; ++src) fsum += fcpart[src][fc_half][fc_lsrc][fc_comp];
    out[((size_t)(n0 + fc_row) * TSTEPS + (TSTEPS - 1)) * DOUT + j0 + fc_col] = fsum;
  }
}

extern "C" void kernel_launch(void* const* d_in, const int* in_sizes, int n_in,
                              void* d_out, int out_size, void* d_ws, size_t ws_size,
                              hipStream_t stream) {
  const float* hT   = (const float*)d_in[0];
  const float* W_ih = (const float*)d_in[1];
  const float* W_hh = (const float*)d_in[2];
  const float* b_ih = (const float*)d_in[3];
  const float* b_hh = (const float*)d_in[4];
  const float* W_fc = (const float*)d_in[5];
  const float* b_fc = (const float*)d_in[6];
  float* out = (float*)d_out;

  char* ws = (char*)d_ws;
  unsigned* flags = (unsigned*)ws;                 // flags[256] + xcd_ctr[8]
  _Float16* hs    = (_Float16*)(ws + 65536);       // 257 * 256KB (slot 0 unused)

  hipMemsetAsync(flags, 0, 4096, stream);          // stream-ordered flag init
  lstm_kernel<<<256, 512, 0, stream>>>(W_ih, W_hh, b_ih, b_hh, hT, W_fc, b_fc,
                                       hs, flags, out);
}

// Round 13
// 959.979 us; speedup vs baseline: 1.0813x; 1.0813x over previous
//
#include <hip/hip_runtime.h>

#define Hh 1024
#define NBATCH 128
#define TSTEPS 256
#define DOUT 1024
#define SLOT (NBATCH * Hh)

typedef _Float16 half8 __attribute__((ext_vector_type(8)));
typedef float floatx4 __attribute__((ext_vector_type(4)));

__device__ __forceinline__ float fast_sigmoid(float x) {
  float e = __expf(-x);
  return __builtin_amdgcn_rcpf(1.0f + e);
}
__device__ __forceinline__ float fast_tanh(float x) {
  x = fminf(15.0f, fmaxf(-15.0f, x));
  float e = __expf(-2.0f * x);
  return 1.0f - 2.0f * e * __builtin_amdgcn_rcpf(1.0f + e);
}

// Convert weights to f16, build W_sum = W_ih + W_hh, b_sum = b_ih + b_hh,
// stage hT as f16 into hs slot 0, zero flags (256) + per-XCD counters (8).
// (Round-10 proven form. v12 showed in-kernel weight staging is a net loss:
// 2x f32 bytes through L3 per XCD + serial conversion at kernel start.)
__global__ void prep_kernel(const float* __restrict__ W_ih, const float* __restrict__ W_hh,
                            const float* __restrict__ W_fc, const float* __restrict__ b_ih,
                            const float* __restrict__ b_hh, const float* __restrict__ hT,
                            _Float16* __restrict__ w_ih_h, _Float16* __restrict__ w_sum_h,
                            _Float16* __restrict__ w_fc_h, float* __restrict__ b_sum,
                            _Float16* __restrict__ hs0, unsigned* __restrict__ flags) {
  int i0 = blockIdx.x * blockDim.x + threadIdx.x;
  int stride = gridDim.x * blockDim.x;
  for (int i = i0; i < 4096 * 1024; i += stride) {
    float a = W_ih[i];
    w_ih_h[i] = (_Float16)a;
    w_sum_h[i] = (_Float16)(a + W_hh[i]);
  }
  for (int i = i0; i < 1024 * 1024; i += stride) w_fc_h[i] = (_Float16)W_fc[i];
  for (int i = i0; i < 4096; i += stride) b_sum[i] = b_ih[i] + b_hh[i];
  for (int i = i0; i < NBATCH * Hh; i += stride) hs0[i] = (_Float16)hT[i];
  for (int i = i0; i < 512; i += stride) flags[i] = 0;  // flags[256] + xcd_ctr[8]
}

// Fused persistent kernel (round-10 proven core: 877us incl. fc): 256 WGs,
// 512 threads = 8 waves, all running the lstm persona at K=128 + distributed
// fc (zero extra A-loads). Sync = v6 discipline verbatim (two __syncthreads,
// drain-then-WG-flag by tid 0, per-wave 4-producer all-lane poll).
//
// v13's single change: the fc reduce + out store move from BETWEEN the two
// barriers (on the producer->consumer critical chain) to AFTER the flag
// store (into the poll-slack window). fcpart becomes a parity double-buffer:
// step s writes fcpart[s&1] pre-barrier1; the reduce of fcpart[s&1] runs
// after barrier2(s)+flag. Adjacent steps use opposite parities; a
// same-parity writer (s+2) starts only after barrier2(s+1), which the
// step-s reader has already passed -> race-free by barrier ordering alone.
// Out stores drain at the NEXT step's barrier2 (end-of-kernel visibility
// is all out needs).
__global__ __launch_bounds__(512, 2) void lstm_kernel(
    const _Float16* __restrict__ w_ih_h, const _Float16* __restrict__ w_sum_h,
    const float* __restrict__ b_sum, _Float16* __restrict__ hs,
    unsigned* __restrict__ flags, const _Float16* __restrict__ w_fc,
    const float* __restrict__ b_fc, float* __restrict__ out) {
  unsigned* xcd_ctr = flags + 256;
  const int tid = threadIdx.x;
  const int wave = tid >> 6;  // 0..7
  const int lane = tid & 63;
  const int l15 = lane & 15;
  const int quad = lane >> 4;

  __shared__ unsigned role_sh;
  {
    unsigned xcd;
    asm volatile("s_getreg_b32 %0, hwreg(HW_REG_XCC_ID)" : "=s"(xcd));
    if (tid == 0) role_sh = (xcd << 8) | atomicAdd(&xcd_ctr[xcd], 1u);
  }
  __syncthreads();
  const int g = role_sh >> 8;    // physical XCD == n-group
  const int jb = role_sh & 255;  // 0..31 within the XCD
  const int n0 = g * 16;
  const int j0 = jb * 32;
  const int kbase = wave * 128;      // this wave's K-range
  const int oc = wave & 1;           // 16-col half of the 32-col j-block
  const int rp = (wave >> 1) & 1;    // accumulator reg-pair
  const int rr = (wave >> 2) & 1;    // element within the pair
  unsigned* gflags = flags + g * 32;
  unsigned* pollp = gflags + wave * 4 + (lane & 3);  // 4 producers cover K-range

  __shared__ float2 part[8][2][4][2][64];     // 64KB lstm partials
  __shared__ floatx4 fcpart[2][8][2][64];     // 2x16KB fc partials (parity dbuf)

  float bias[4];
#pragma unroll
  for (int gt = 0; gt < 4; ++gt) bias[gt] = b_sum[gt * 1024 + j0 + oc * 16 + l15];

  // fc reduce role: thread tid owns out element (row fc_row, col fc_col)
  const int fc_col = tid & 31;
  const int fc_row = tid >> 5;  // 0..15
  const float bfc = b_fc[j0 + fc_col];
  const int fc_half = fc_col >> 4;
  const int fc_lsrc = (fc_row >> 2) * 16 + (fc_col & 15);
  const int fc_comp = fc_row & 3;

  half8 B[4][2][4];   // 128 regs lstm weights
  half8 Bfc[2][4];    // 32 regs fc weights (this wave's K-chunk)
  float cst = 0.0f;   // persistent cell state

  auto load_B = [&](const _Float16* w) {
#pragma unroll
    for (int gt = 0; gt < 4; ++gt)
#pragma unroll
      for (int ct = 0; ct < 2; ++ct) {
        const _Float16* p =
            w + (size_t)(gt * 1024 + j0 + ct * 16 + l15) * Hh + kbase + quad * 8;
#pragma unroll
        for (int ks = 0; ks < 4; ++ks) B[gt][ct][ks] = *(const half8*)(p + ks * 32);
      }
  };
  {
#pragma unroll
    for (int ct = 0; ct < 2; ++ct) {
      const _Float16* p = w_fc + (size_t)(j0 + ct * 16 + l15) * Hh + kbase + quad * 8;
#pragma unroll
      for (int ks = 0; ks < 4; ++ks) Bfc[ct][ks] = *(const half8*)(p + ks * 32);
    }
  }

  auto poll = [&](int tgt) {
    while (1) {
      unsigned v = __hip_atomic_load(pollp, __ATOMIC_RELAXED, __HIP_MEMORY_SCOPE_AGENT);
      if (__all((int)(v >= (unsigned)tgt))) break;
    }
  };

  auto fc_reduce = [&](int pb, int col) {
    float fsum = bfc;
#pragma unroll
    for (int src = 0; src < 8; ++src)
      fsum += fcpart[pb][src][fc_half][fc_lsrc][fc_comp];
    out[((size_t)(n0 + fc_row) * TSTEPS + col) * DOUT + j0 + fc_col] = fsum;
  };

  auto do_step = [&](const _Float16* hsrc, _Float16* hdst, int s) {
    poll(s);
    floatx4 acc[2][4] = {};
    floatx4 f0 = {}, f1 = {};
    const _Float16* ap = hsrc + (size_t)(n0 + l15) * Hh + kbase + quad * 8;
#pragma unroll
    for (int ks = 0; ks < 4; ++ks) {
      half8 a = *(const half8*)(ap + ks * 32);
#pragma unroll
      for (int ct = 0; ct < 2; ++ct)
#pragma unroll
        for (int gt = 0; gt < 4; ++gt)
          acc[ct][gt] =
              __builtin_amdgcn_mfma_f32_16x16x32_f16(a, B[gt][ct][ks], acc[ct][gt], 0, 0, 0);
      if (s >= 1) {  // slot 0 = hT, not an fc input
        f0 = __builtin_amdgcn_mfma_f32_16x16x32_f16(a, Bfc[0][ks], f0, 0, 0, 0);
        f1 = __builtin_amdgcn_mfma_f32_16x16x32_f16(a, Bfc[1][ks], f1, 0, 0, 0);
      }
    }
#pragma unroll
    for (int ct = 0; ct < 2; ++ct)
#pragma unroll
      for (int gt = 0; gt < 4; ++gt) {
        float2 lo, hi;
        lo.x = acc[ct][gt][0]; lo.y = acc[ct][gt][1];
        hi.x = acc[ct][gt][2]; hi.y = acc[ct][gt][3];
        part[wave][ct][gt][0][lane] = lo;
        part[wave][ct][gt][1][lane] = hi;
      }
    if (s >= 1) {
      fcpart[s & 1][wave][0][lane] = f0;
      fcpart[s & 1][wave][1][lane] = f1;
    }
    __syncthreads();

    float gv[4];
#pragma unroll
    for (int gt = 0; gt < 4; ++gt) {
      float s2 = bias[gt];
#pragma unroll
      for (int src = 0; src < 8; ++src) {
        float2 p = part[src][oc][gt][rp][lane];
        s2 += rr ? p.y : p.x;
      }
      gv[gt] = s2;
    }
    {
      float ig = fast_sigmoid(gv[0]);
      float fg = fast_sigmoid(gv[1]);
      float gg = fast_tanh(gv[2]);
      float og = fast_sigmoid(gv[3]);
      float c = fg * cst + ig * gg;
      cst = c;
      float h = og * fast_tanh(c);
      int row = n0 + quad * 4 + rp * 2 + rr;
      _Float16 hv = (_Float16)h;
      unsigned short ub;
      __builtin_memcpy(&ub, &hv, 2);
      // agent write-through store (v6-proven); next barrier drains vmcnt.
      __hip_atomic_store((unsigned short*)(hdst + (size_t)row * Hh + j0 + oc * 16 + l15),
                         ub, __ATOMIC_RELAXED, __HIP_MEMORY_SCOPE_AGENT);
    }
    __syncthreads();  // drain: all h stores retired at coherent point
    if (tid == 0) {
      __hip_atomic_store(&gflags[jb], (unsigned)(s + 1), __ATOMIC_RELAXED,
                         __HIP_MEMORY_SCOPE_AGENT);
    }
    // Deferred fc reduce: off the critical chain, in the poll-slack window.
    if (s >= 1) fc_reduce(s & 1, s - 1);
  };

  // Step 0: x = hT, hx = 0  =>  gates = hT @ W_ih^T + b_sum
  load_B(w_ih_h);
  do_step(hs, hs + SLOT, 0);
  // Steps 1..255: x = hx = h  =>  gates = h @ (W_ih+W_hh)^T + b_sum
  load_B(w_sum_h);
  for (int s = 1; s < TSTEPS; ++s)
    do_step(hs + (size_t)s * SLOT, hs + (size_t)(s + 1) * SLOT, s);

  // Epilogue: fc for slot 256 (out col 255), parity-0 buffer (safe: last
  // parity-0 reduce finished before barrier2(255), which all waves passed).
  {
    unsigned* ep = gflags + (lane & 31);
    while (1) {
      unsigned v = __hip_atomic_load(ep, __ATOMIC_RELAXED, __HIP_MEMORY_SCOPE_AGENT);
      if (__all((int)(v >= (unsigned)TSTEPS))) break;
    }
    asm volatile("" ::: "memory");
    floatx4 f0 = {}, f1 = {};
    const _Float16* ap =
        hs + (size_t)TSTEPS * SLOT + (size_t)(n0 + l15) * Hh + kbase + quad * 8;
#pragma unroll
    for (int ks = 0; ks < 4; ++ks) {
      half8 a = *(const half8*)(ap + ks * 32);
      f0 = __builtin_amdgcn_mfma_f32_16x16x32_f16(a, Bfc[0][ks], f0, 0, 0, 0);
      f1 = __builtin_amdgcn_mfma_f32_16x16x32_f16(a, Bfc[1][ks], f1, 0, 0, 0);
    }
    fcpart[0][wave][0][lane] = f0;
    fcpart[0][wave][1][lane] = f1;
    __syncthreads();
    fc_reduce(0, TSTEPS - 1);
  }
}

extern "C" void kernel_launch(void* const* d_in, const int* in_sizes, int n_in,
                              void* d_out, int out_size, void* d_ws, size_t ws_size,
                              hipStream_t stream) {
  const float* hT   = (const float*)d_in[0];
  const float* W_ih = (const float*)d_in[1];
  const float* W_hh = (const float*)d_in[2];
  const float* b_ih = (const float*)d_in[3];
  const float* b_hh = (const float*)d_in[4];
  const float* W_fc = (const float*)d_in[5];
  const float* b_fc = (const float*)d_in[6];
  float* out = (float*)d_out;

  char* ws = (char*)d_ws;
  unsigned* flags   = (unsigned*)ws;                    // flags[256] + xcd_ctr[8]
  float* b_sum      = (float*)(ws + 4096);              // 16KB
  _Float16* w_ih_h  = (_Float16*)(ws + 65536);          // 8MB
  _Float16* w_sum_h = w_ih_h + (size_t)4096 * 1024;     // 8MB
  _Float16* w_fc_h  = w_sum_h + (size_t)4096 * 1024;    // 2MB
  _Float16* hs      = w_fc_h + (size_t)1024 * 1024;     // 257 * 256KB = 67.3MB

  prep_kernel<<<4096, 256, 0, stream>>>(W_ih, W_hh, W_fc, b_ih, b_hh, hT,
                                        w_ih_h, w_sum_h, w_fc_h, b_sum, hs, flags);
  lstm_kernel<<<256, 512, 0, stream>>>(w_ih_h, w_sum_h, b_sum, hs, flags,
                                       w_fc_h, b_fc, out);
}